// Round 6
// baseline (259.972 us; speedup 1.0000x reference)
//
#include <hip/hip_runtime.h>
#include <math.h>

#define NB    16
#define NAg   3
#define NCg   85
#define NCLS  80
#define NGg   76
#define NSp   (NGg*NGg)     // 5776
#define NCELL (NAg*NSp)     // 17328
#define NBOX  50
#define INCH  256
#define CHUNK 16            // channels staged per LDS buffer
#define NTILE 23            // ceil(5776/256) spatial tiles

// ws layout (bytes)
#define ACC_OFF  0                                  // 8 floats
#define WIN_OFF  32                                 // NB*NCELL ints = 1,108,992
#define GD_OFF   (WIN_OFF + NB*NCELL*4)             // NB*NBOX*10 floats
#define GI_OFF   (GD_OFF + NB*NBOX*10*4)            // NB*NBOX*2 ints
#define PART_OFF (GI_OFF + NB*NBOX*2*4)             // NB*15*NSp floats = 5,544,960
#define ZERO_BYTES GD_OFF                           // acc + win

__device__ __constant__ float c_AW[9] = {1.25f,2.0f,4.125f,3.75f,7.75f,7.375f,14.5f,19.5f,46.625f};
__device__ __constant__ float c_AH[9] = {1.625f,3.75f,2.875f,7.625f,5.625f,14.875f,11.25f,24.75f,40.75f};
__device__ __constant__ int   c_ROW[15] = {0,1,2,3,4, 85,86,87,88,89, 170,171,172,173,174};

__device__ __forceinline__ float safe_log(float p) {
    return fmaxf(logf(fmaxf(p, 1e-12f)), -100.0f);
}
__device__ __forceinline__ float sigm(float x) {
    return 1.0f / (1.0f + expf(-x));
}

// ---- Kernel 1: LDS-staged transposed 15-ch GEMM ---------------------------
// block=256: thread owns ONE spatial element -> acc = 15 scalar VGPRs.
// X streamed in 16-ch chunks, double-buffered LDS; W staged once (broadcast).
__global__ __launch_bounds__(256) void k_gemm_lds(
    const float* __restrict__ xin, const float* __restrict__ W,
    float* __restrict__ part)
{
    __shared__ float wsm[15][256];            // 15 KiB
    __shared__ float xs[2][CHUNK][256];       // 32 KiB

    const int tid = threadIdx.x;
    const int b   = blockIdx.y;
    const int sp0 = blockIdx.x * 256;

    // stage W rows (one-time)
    for (int idx = tid; idx < 15 * 256; idx += 256) {
        const int f = idx >> 8, c = idx & 255;
        wsm[f][c] = W[(size_t)c_ROW[f] * INCH + c];
    }

    // loader mapping: lane spatial-quad + channel-within-4
    const int lsp = (tid & 63) * 4;           // 0..252
    const int lch = tid >> 6;                 // 0..3
    int spl = sp0 + lsp;
    if (spl > NSp - 4) spl = NSp - 4;         // clamp tail (dupes discarded)
    const float* xb = xin + (size_t)b * INCH * NSp + spl;

    float4 xv[4];
#pragma unroll
    for (int i = 0; i < 4; i++)               // preload chunk 0 (ch 0..15)
        xv[i] = *(const float4*)(xb + (size_t)(lch + 4*i) * NSp);
    __syncthreads();                          // wsm ready
#pragma unroll
    for (int i = 0; i < 4; i++)
        *(float4*)&xs[0][lch + 4*i][lsp] = xv[i];

    float acc[15];
#pragma unroll
    for (int f = 0; f < 15; f++) acc[f] = 0.f;

    for (int k = 0; k < INCH / CHUNK; k++) {  // 16 chunks
        const int buf = k & 1;
        if (k + 1 < INCH / CHUNK) {
            const int c0 = (k + 1) * CHUNK;
#pragma unroll
            for (int i = 0; i < 4; i++)       // 4 independent loads in flight
                xv[i] = *(const float4*)(xb + (size_t)(c0 + lch + 4*i) * NSp);
        }
        __syncthreads();                      // prev compute done; xs[buf] valid
        if (k + 1 < INCH / CHUNK) {
#pragma unroll
            for (int i = 0; i < 4; i++)
                *(float4*)&xs[buf ^ 1][lch + 4*i][lsp] = xv[i];
        }
        const int cb = k * CHUNK;
#pragma unroll
        for (int cg = 0; cg < CHUNK; cg += 4) {
            const float x0 = xs[buf][cg+0][tid];
            const float x1 = xs[buf][cg+1][tid];
            const float x2 = xs[buf][cg+2][tid];
            const float x3 = xs[buf][cg+3][tid];
#pragma unroll
            for (int f = 0; f < 15; f++) {
                const float4 wv = *(const float4*)&wsm[f][cb + cg];  // broadcast
                acc[f] += wv.x*x0 + wv.y*x1 + wv.z*x2 + wv.w*x3;
            }
        }
    }

    const int s = sp0 + tid;
    if (s < NSp) {
#pragma unroll
        for (int f = 0; f < 15; f++)
            part[((size_t)b * 15 + f) * NSp + s] = acc[f];
    }
}

// ---- Kernel 2: label processing + winner scatter --------------------------
__global__ void k_labels(const float* __restrict__ labels,
                         float* __restrict__ gdata, int* __restrict__ gint,
                         int* __restrict__ win)
{
    int t = blockIdx.x * blockDim.x + threadIdx.x;
    if (t >= NB * NBOX) return;
    int b = t / NBOX, n = t % NBOX;

    const float* L = labels + (size_t)t * 5;
    float l0 = L[0], l1 = L[1], l2 = L[2], l3 = L[3], l4 = L[4];
    int valid = (l0 + l1 + l2 + l3 + l4) > 0.f;

    float gx = l1 * NGg, gy = l2 * NGg, gw = l3 * NGg, gh = l4 * NGg;

    int best = 0; float brr = -1.f;
#pragma unroll
    for (int k = 0; k < 9; k++) {
        float inter = fminf(gw, c_AW[k]) * fminf(gh, c_AH[k]);
        float uni   = gw*gh + c_AW[k]*c_AH[k] - inter;
        float r     = inter / uni;
        if (r > brr) { brr = r; best = k; }   // first max wins (argmax)
    }
    int a = (best <= 2) ? best : -1;
    int assign = valid && (a >= 0);
    int a_safe = a < 0 ? 0 : (a > 2 ? 2 : a);

    float* gd = gdata + (size_t)t * 10;
    gd[0] = gx; gd[1] = gy; gd[2] = gw; gd[3] = gh;
    gd[4] = gx - floorf(gx);
    gd[5] = gy - floorf(gy);
    gd[6] = logf(gw / c_AW[a_safe] + 1e-16f);
    gd[7] = logf(gh / c_AH[a_safe] + 1e-16f);
    gd[8] = 2.f - gw * gh / (float)NSp;
    gd[9] = valid ? 1.f : 0.f;

    int gi = (int)floorf(gx), gj = (int)floorf(gy);
    int inb = (gi >= 0) && (gi < NGg) && (gj >= 0) && (gj < NGg);
    int cell = (assign && inb) ? (a * NSp + gj * NGg + gi) : -1;
    gint[t*2 + 0] = cell;
    gint[t*2 + 1] = (int)l0;

    if (cell >= 0) atomicMax(&win[b * NCELL + cell], n + 1);  // last index wins
}

// ---- Kernel 3: fused decode + best-IoU + obj BCE --------------------------
__global__ __launch_bounds__(256) void k_fuse(
    const float* __restrict__ part, const float* __restrict__ bias,
    const float* __restrict__ gdata, const int* __restrict__ win,
    float* __restrict__ acc)
{
    __shared__ float sb[NBOX][5];
    __shared__ int sHas;
    __shared__ float red[256];

    const int b = blockIdx.y;
    const int tid = threadIdx.x;

    if (tid < NBOX) {
        const float* gd = gdata + ((size_t)b * NBOX + tid) * 10;
        sb[tid][0] = gd[0]; sb[tid][1] = gd[1];
        sb[tid][2] = gd[2]; sb[tid][3] = gd[3];
        sb[tid][4] = gd[9];
    }
    if (tid == 0) sHas = 0;
    __syncthreads();
    if (tid < NBOX && sb[tid][4] > 0.f) atomicOr(&sHas, 1);
    __syncthreads();

    const int cell = blockIdx.x * 256 + tid;
    float l = 0.f;
    if (cell < NCELL) {
        const int a = cell / NSp, s = cell % NSp;
        const float* pp = part + ((size_t)b * 15 + a * 5) * NSp + s;
        float x0 = pp[0*NSp], x1 = pp[1*NSp], x2 = pp[2*NSp];
        float x3 = pp[3*NSp], x4 = pp[4*NSp];
        const float gxf = (float)(s % NGg);
        const float gyf = (float)(s / NGg);
        float px = sigm(x0 + bias[a*NCg+0]) + gxf;
        float py = sigm(x1 + bias[a*NCg+1]) + gyf;
        float pw = expf(x2 + bias[a*NCg+2]) * c_AW[a];
        float ph = expf(x3 + bias[a*NCg+3]) * c_AH[a];
        float cf = sigm(x4 + bias[a*NCg+4]);
        float pa = pw * ph;
        float bi = 0.f;
        for (int n = 0; n < NBOX; n++) {
            if (sb[n][4] > 0.f) {
                float gx = sb[n][0], gy = sb[n][1], gw = sb[n][2], gh = sb[n][3];
                float tlx = fmaxf(px - pw*0.5f, gx - gw*0.5f);
                float tly = fmaxf(py - ph*0.5f, gy - gh*0.5f);
                float brx = fminf(px + pw*0.5f, gx + gw*0.5f);
                float bry = fminf(py + ph*0.5f, gy + gh*0.5f);
                float inter = ((tlx < brx) && (tly < bry)) ? (brx-tlx)*(bry-tly) : 0.f;
                float iou = inter / (pa + gw*gh - inter);
                bi = fmaxf(bi, iou);
            }
        }
        bool maskpre  = sHas ? (bi <= 0.7f) : true;
        bool assigned = win[b * NCELL + cell] > 0;
        if (maskpre || assigned) {
            float t = assigned ? 1.f : 0.f;
            l = -(t * safe_log(cf) + (1.f - t) * safe_log(1.f - cf));
        }
    }
    red[tid] = l;
    __syncthreads();
    for (int o = 128; o > 0; o >>= 1) {
        if (tid < o) red[tid] += red[tid + o];
        __syncthreads();
    }
    if (tid == 0) atomicAdd(&acc[2], red[0]);
}

// ---- Kernel 4: per-assigned-cell xy/wh/cls losses -------------------------
__global__ __launch_bounds__(256) void k_assigned(
    const float* __restrict__ xin, const float* __restrict__ W,
    const float* __restrict__ bias, const float* __restrict__ gdata,
    const int* __restrict__ gint, const int* __restrict__ win,
    float* __restrict__ acc)
{
    const int t = blockIdx.x;            // box id 0..799
    const int b = t / NBOX, n = t % NBOX;
    const int cell = gint[t*2];
    if (cell < 0) return;
    if (win[b * NCELL + cell] != n + 1) return;   // only the winning box writes

    const int a = cell / NSp, s = cell % NSp;
    const int o0 = a * NCg;
    const int tid = threadIdx.x;

    __shared__ float4 col4[64];
    __shared__ float  xsh[NCg];
    __shared__ float  sacc[3];

    ((float*)col4)[tid] = xin[((size_t)b * INCH + tid) * NSp + s];
    if (tid < 3) sacc[tid] = 0.f;
    __syncthreads();

    const int wid = tid >> 6, lane = tid & 63;
    for (int o = wid; o < NCg; o += 4) {
        const float4 wv = *(const float4*)&W[(size_t)(o0 + o) * INCH + lane * 4];
        const float4 cv = col4[lane];
        float p = wv.x*cv.x + wv.y*cv.y + wv.z*cv.z + wv.w*cv.w;
        for (int off = 32; off; off >>= 1) p += __shfl_down(p, off);
        if (lane == 0) xsh[o] = p + bias[o0 + o];
    }
    __syncthreads();

    if (tid < NCg) {
        const float* gd = gdata + (size_t)t * 10;
        const float sval = gd[8];
        const int gcls = gint[t*2 + 1];
        float val = xsh[tid];
        float term; int slot;
        if (tid < 2) {                       // xy BCE * sval
            float tgt = gd[4 + tid];
            float p = sigm(val);
            term = -(tgt * safe_log(p) + (1.f - tgt) * safe_log(1.f - p)) * sval;
            slot = 0;
        } else if (tid < 4) {                // wh MSE * 0.5*sval
            float tgt = gd[4 + tid];
            float d = val - tgt;
            term = 0.5f * sval * d * d;
            slot = 1;
        } else if (tid == 4) {               // conf handled in k_fuse
            term = 0.f; slot = 2;
        } else {                             // cls BCE
            float tgt = ((tid - 5) == gcls) ? 1.f : 0.f;
            float p = sigm(val);
            term = -(tgt * safe_log(p) + (1.f - tgt) * safe_log(1.f - p));
            slot = 2;
        }
        atomicAdd(&sacc[slot], term);
    }
    __syncthreads();
    if (tid == 0) {
        atomicAdd(&acc[0], sacc[0]);
        atomicAdd(&acc[1], sacc[1]);
        atomicAdd(&acc[3], sacc[2]);
    }
}

// ---- Kernel 5: finalize ---------------------------------------------------
__global__ void k_final(const float* __restrict__ acc, float* __restrict__ out)
{
    float xy = acc[0], wh = acc[1], ob = acc[2], cl = acc[3];
    out[0] = xy + wh + ob + cl;
    out[1] = xy; out[2] = wh; out[3] = ob; out[4] = cl;
}

extern "C" void kernel_launch(void* const* d_in, const int* in_sizes, int n_in,
                              void* d_out, int out_size, void* d_ws, size_t ws_size,
                              hipStream_t stream)
{
    const float* xin    = (const float*)d_in[0];
    const float* labels = (const float*)d_in[1];
    const float* W      = (const float*)d_in[2];
    const float* bias   = (const float*)d_in[3];

    char* ws = (char*)d_ws;
    float* acc   = (float*)(ws + ACC_OFF);
    int*   win   = (int*)  (ws + WIN_OFF);
    float* gdata = (float*)(ws + GD_OFF);
    int*   gint  = (int*)  (ws + GI_OFF);
    float* part  = (float*)(ws + PART_OFF);
    float* out   = (float*)d_out;

    hipMemsetAsync(ws, 0, ZERO_BYTES, stream);   // acc + win only

    k_labels  <<<dim3((NB*NBOX + 255)/256), 256, 0, stream>>>(labels, gdata, gint, win);
    k_gemm_lds<<<dim3(NTILE, NB), 256, 0, stream>>>(xin, W, part);
    k_fuse    <<<dim3((NCELL + 255)/256, NB), 256, 0, stream>>>(part, bias, gdata, win, acc);
    k_assigned<<<dim3(NB*NBOX), 256, 0, stream>>>(xin, W, bias, gdata, gint, win, acc);
    k_final   <<<1, 1, 0, stream>>>(acc, out);
}

// Round 7
// 205.982 us; speedup vs baseline: 1.2621x; 1.2621x over previous
//
#include <hip/hip_runtime.h>
#include <math.h>

#define NB    16
#define NAg   3
#define NCg   85
#define NCLS  80
#define NGg   76
#define NSp   (NGg*NGg)     // 5776
#define NG2   (NSp/2)       // 2888 float2 groups per image
#define NCELL (NAg*NSp)     // 17328
#define NBOX  50
#define INCH  256

// ws layout (bytes)
#define ACC_OFF  0                                  // 8 floats
#define WIN_OFF  32                                 // NB*NCELL ints   = 1,108,992
#define GD_OFF   (WIN_OFF + NB*NCELL*4)             // NB*NBOX*10 floats
#define GI_OFF   (GD_OFF + NB*NBOX*10*4)            // NB*NBOX*2 ints
#define PART_OFF (GI_OFF + NB*NBOX*2*4)             // NSLICE*NB*15*NSp floats
#define PART_SZ1 ((size_t)NB*15*NSp*4)              // 5,544,960 per slice
#define NEED4    (PART_OFF + 4*PART_SZ1)            // ~23.3 MB
#define ZERO_BYTES GD_OFF                           // acc + win

__device__ __constant__ float c_AW[9] = {1.25f,2.0f,4.125f,3.75f,7.75f,7.375f,14.5f,19.5f,46.625f};
__device__ __constant__ float c_AH[9] = {1.625f,3.75f,2.875f,7.625f,5.625f,14.875f,11.25f,24.75f,40.75f};
__device__ __constant__ int   c_ROW[15] = {0,1,2,3,4, 85,86,87,88,89, 170,171,172,173,174};

__device__ __forceinline__ float safe_log(float p) {
    return fmaxf(logf(fmaxf(p, 1e-12f)), -100.0f);
}
__device__ __forceinline__ float sigm(float x) {
    return 1.0f / (1.0f + expf(-x));
}

// ---- Kernel 1: streaming partial GEMM, W in LDS (broadcast b128) ----------
// float2 spatial/thread -> acc = 30 VGPRs. No barriers in the K-loop.
// NSLICE=4: grid (12, 16, 4) = 768 blocks = 12 waves/CU.
template<int NSLICE>
__global__ __launch_bounds__(256) void k_gemm_w(
    const float* __restrict__ xin, const float* __restrict__ W,
    float* __restrict__ part)
{
    constexpr int CPS = INCH / NSLICE;               // 64
    __shared__ float wsm[15][CPS];

    const int tid = threadIdx.x;
    const int b   = blockIdx.y;
    const int sl  = blockIdx.z;

    for (int idx = tid; idx < 15 * CPS; idx += 256) {
        const int f = idx / CPS, c = idx % CPS;
        wsm[f][c] = W[(size_t)c_ROW[f] * INCH + sl * CPS + c];
    }
    __syncthreads();                                 // only barrier

    const int g = blockIdx.x * 256 + tid;            // float2 group id
    if (g >= NG2) return;
    const int s0 = g * 2;

    float2 acc[15];
#pragma unroll
    for (int f = 0; f < 15; f++) acc[f] = make_float2(0.f, 0.f);

    const float* xp = xin + ((size_t)b * INCH + sl * CPS) * NSp + s0;

#pragma unroll 4
    for (int g4 = 0; g4 < CPS / 4; g4++) {
        const float2 xv0 = *(const float2*)(xp + (size_t)(g4*4+0) * NSp);
        const float2 xv1 = *(const float2*)(xp + (size_t)(g4*4+1) * NSp);
        const float2 xv2 = *(const float2*)(xp + (size_t)(g4*4+2) * NSp);
        const float2 xv3 = *(const float2*)(xp + (size_t)(g4*4+3) * NSp);
#pragma unroll
        for (int f = 0; f < 15; f++) {
            const float4 wv = *(const float4*)&wsm[f][g4*4];   // LDS broadcast
            acc[f].x += wv.x*xv0.x + wv.y*xv1.x + wv.z*xv2.x + wv.w*xv3.x;
            acc[f].y += wv.x*xv0.y + wv.y*xv1.y + wv.z*xv2.y + wv.w*xv3.y;
        }
    }
#pragma unroll
    for (int f = 0; f < 15; f++)
        *(float2*)&part[(((size_t)sl * NB + b) * 15 + f) * NSp + s0] = acc[f];
}

// ---- Kernel 2: label processing + winner scatter --------------------------
__global__ void k_labels(const float* __restrict__ labels,
                         float* __restrict__ gdata, int* __restrict__ gint,
                         int* __restrict__ win)
{
    int t = blockIdx.x * blockDim.x + threadIdx.x;
    if (t >= NB * NBOX) return;
    int b = t / NBOX, n = t % NBOX;

    const float* L = labels + (size_t)t * 5;
    float l0 = L[0], l1 = L[1], l2 = L[2], l3 = L[3], l4 = L[4];
    int valid = (l0 + l1 + l2 + l3 + l4) > 0.f;

    float gx = l1 * NGg, gy = l2 * NGg, gw = l3 * NGg, gh = l4 * NGg;

    int best = 0; float brr = -1.f;
#pragma unroll
    for (int k = 0; k < 9; k++) {
        float inter = fminf(gw, c_AW[k]) * fminf(gh, c_AH[k]);
        float uni   = gw*gh + c_AW[k]*c_AH[k] - inter;
        float r     = inter / uni;
        if (r > brr) { brr = r; best = k; }   // first max wins (argmax)
    }
    int a = (best <= 2) ? best : -1;
    int assign = valid && (a >= 0);
    int a_safe = a < 0 ? 0 : (a > 2 ? 2 : a);

    float* gd = gdata + (size_t)t * 10;
    gd[0] = gx; gd[1] = gy; gd[2] = gw; gd[3] = gh;
    gd[4] = gx - floorf(gx);
    gd[5] = gy - floorf(gy);
    gd[6] = logf(gw / c_AW[a_safe] + 1e-16f);
    gd[7] = logf(gh / c_AH[a_safe] + 1e-16f);
    gd[8] = 2.f - gw * gh / (float)NSp;
    gd[9] = valid ? 1.f : 0.f;

    int gi = (int)floorf(gx), gj = (int)floorf(gy);
    int inb = (gi >= 0) && (gi < NGg) && (gj >= 0) && (gj < NGg);
    int cell = (assign && inb) ? (a * NSp + gj * NGg + gi) : -1;
    gint[t*2 + 0] = cell;
    gint[t*2 + 1] = (int)l0;

    if (cell >= 0) atomicMax(&win[b * NCELL + cell], n + 1);  // last index wins
}

// ---- Kernel 3: fused reduce + decode + best-IoU + obj BCE -----------------
template<int NSLICE>
__global__ __launch_bounds__(256) void k_fuse(
    const float* __restrict__ part, const float* __restrict__ bias,
    const float* __restrict__ gdata, const int* __restrict__ win,
    float* __restrict__ acc)
{
    __shared__ float sb[NBOX][5];
    __shared__ int sHas;
    __shared__ float red[256];

    const int b = blockIdx.y;
    const int tid = threadIdx.x;

    if (tid < NBOX) {
        const float* gd = gdata + ((size_t)b * NBOX + tid) * 10;
        sb[tid][0] = gd[0]; sb[tid][1] = gd[1];
        sb[tid][2] = gd[2]; sb[tid][3] = gd[3];
        sb[tid][4] = gd[9];
    }
    if (tid == 0) sHas = 0;
    __syncthreads();
    if (tid < NBOX && sb[tid][4] > 0.f) atomicOr(&sHas, 1);
    __syncthreads();

    const int cell = blockIdx.x * 256 + tid;
    float l = 0.f;
    if (cell < NCELL) {
        const int a = cell / NSp, s = cell % NSp;
        float x0 = 0.f, x1 = 0.f, x2 = 0.f, x3 = 0.f, x4 = 0.f;
#pragma unroll
        for (int sl = 0; sl < NSLICE; sl++) {
            const float* pp = part + (((size_t)sl * NB + b) * 15 + a * 5) * NSp + s;
            x0 += pp[0*NSp]; x1 += pp[1*NSp]; x2 += pp[2*NSp];
            x3 += pp[3*NSp]; x4 += pp[4*NSp];
        }
        const float gxf = (float)(s % NGg);
        const float gyf = (float)(s / NGg);
        float px = sigm(x0 + bias[a*NCg+0]) + gxf;
        float py = sigm(x1 + bias[a*NCg+1]) + gyf;
        float pw = expf(x2 + bias[a*NCg+2]) * c_AW[a];
        float ph = expf(x3 + bias[a*NCg+3]) * c_AH[a];
        float cf = sigm(x4 + bias[a*NCg+4]);
        float pa = pw * ph;
        float bi = 0.f;
        for (int n = 0; n < NBOX; n++) {
            if (sb[n][4] > 0.f) {
                float gx = sb[n][0], gy = sb[n][1], gw = sb[n][2], gh = sb[n][3];
                float tlx = fmaxf(px - pw*0.5f, gx - gw*0.5f);
                float tly = fmaxf(py - ph*0.5f, gy - gh*0.5f);
                float brx = fminf(px + pw*0.5f, gx + gw*0.5f);
                float bry = fminf(py + ph*0.5f, gy + gh*0.5f);
                float inter = ((tlx < brx) && (tly < bry)) ? (brx-tlx)*(bry-tly) : 0.f;
                float iou = inter / (pa + gw*gh - inter);
                bi = fmaxf(bi, iou);
            }
        }
        bool maskpre  = sHas ? (bi <= 0.7f) : true;
        bool assigned = win[b * NCELL + cell] > 0;
        if (maskpre || assigned) {
            float t = assigned ? 1.f : 0.f;
            l = -(t * safe_log(cf) + (1.f - t) * safe_log(1.f - cf));
        }
    }
    red[tid] = l;
    __syncthreads();
    for (int o = 128; o > 0; o >>= 1) {
        if (tid < o) red[tid] += red[tid + o];
        __syncthreads();
    }
    if (tid == 0) atomicAdd(&acc[2], red[0]);
}

// ---- Kernel 4: per-assigned-cell xy/wh/cls losses -------------------------
__global__ __launch_bounds__(256) void k_assigned(
    const float* __restrict__ xin, const float* __restrict__ W,
    const float* __restrict__ bias, const float* __restrict__ gdata,
    const int* __restrict__ gint, const int* __restrict__ win,
    float* __restrict__ acc)
{
    const int t = blockIdx.x;            // box id 0..799
    const int b = t / NBOX, n = t % NBOX;
    const int cell = gint[t*2];
    if (cell < 0) return;
    if (win[b * NCELL + cell] != n + 1) return;   // only the winning box writes

    const int a = cell / NSp, s = cell % NSp;
    const int o0 = a * NCg;
    const int tid = threadIdx.x;

    __shared__ float4 col4[64];
    __shared__ float  xsh[NCg];
    __shared__ float  sacc[3];

    ((float*)col4)[tid] = xin[((size_t)b * INCH + tid) * NSp + s];
    if (tid < 3) sacc[tid] = 0.f;
    __syncthreads();

    const int wid = tid >> 6, lane = tid & 63;
    for (int o = wid; o < NCg; o += 4) {
        const float4 wv = *(const float4*)&W[(size_t)(o0 + o) * INCH + lane * 4];
        const float4 cv = col4[lane];
        float p = wv.x*cv.x + wv.y*cv.y + wv.z*cv.z + wv.w*cv.w;
        for (int off = 32; off; off >>= 1) p += __shfl_down(p, off);
        if (lane == 0) xsh[o] = p + bias[o0 + o];
    }
    __syncthreads();

    if (tid < NCg) {
        const float* gd = gdata + (size_t)t * 10;
        const float sval = gd[8];
        const int gcls = gint[t*2 + 1];
        float val = xsh[tid];
        float term; int slot;
        if (tid < 2) {                       // xy BCE * sval
            float tgt = gd[4 + tid];
            float p = sigm(val);
            term = -(tgt * safe_log(p) + (1.f - tgt) * safe_log(1.f - p)) * sval;
            slot = 0;
        } else if (tid < 4) {                // wh MSE * 0.5*sval
            float tgt = gd[4 + tid];
            float d = val - tgt;
            term = 0.5f * sval * d * d;
            slot = 1;
        } else if (tid == 4) {               // conf handled in k_fuse
            term = 0.f; slot = 2;
        } else {                             // cls BCE
            float tgt = ((tid - 5) == gcls) ? 1.f : 0.f;
            float p = sigm(val);
            term = -(tgt * safe_log(p) + (1.f - tgt) * safe_log(1.f - p));
            slot = 2;
        }
        atomicAdd(&sacc[slot], term);
    }
    __syncthreads();
    if (tid == 0) {
        atomicAdd(&acc[0], sacc[0]);
        atomicAdd(&acc[1], sacc[1]);
        atomicAdd(&acc[3], sacc[2]);
    }
}

// ---- Kernel 5: finalize ---------------------------------------------------
__global__ void k_final(const float* __restrict__ acc, float* __restrict__ out)
{
    float xy = acc[0], wh = acc[1], ob = acc[2], cl = acc[3];
    out[0] = xy + wh + ob + cl;
    out[1] = xy; out[2] = wh; out[3] = ob; out[4] = cl;
}

extern "C" void kernel_launch(void* const* d_in, const int* in_sizes, int n_in,
                              void* d_out, int out_size, void* d_ws, size_t ws_size,
                              hipStream_t stream)
{
    const float* xin    = (const float*)d_in[0];
    const float* labels = (const float*)d_in[1];
    const float* W      = (const float*)d_in[2];
    const float* bias   = (const float*)d_in[3];

    char* ws = (char*)d_ws;
    float* acc   = (float*)(ws + ACC_OFF);
    int*   win   = (int*)  (ws + WIN_OFF);
    float* gdata = (float*)(ws + GD_OFF);
    int*   gint  = (int*)  (ws + GI_OFF);
    float* part  = (float*)(ws + PART_OFF);
    float* out   = (float*)d_out;

    hipMemsetAsync(ws, 0, ZERO_BYTES, stream);   // acc + win only

    k_labels<<<dim3((NB*NBOX + 255)/256), 256, 0, stream>>>(labels, gdata, gint, win);

    const int gx = (NG2 + 255) / 256;            // 12
    const int fx = (NCELL + 255) / 256;          // 68

    if (ws_size >= (size_t)NEED4) {
        k_gemm_w<4><<<dim3(gx, NB, 4), 256, 0, stream>>>(xin, W, part);
        k_fuse<4>  <<<dim3(fx, NB),    256, 0, stream>>>(part, bias, gdata, win, acc);
    } else {
        k_gemm_w<1><<<dim3(gx, NB, 1), 256, 0, stream>>>(xin, W, part);
        k_fuse<1>  <<<dim3(fx, NB),    256, 0, stream>>>(part, bias, gdata, win, acc);
    }

    k_assigned<<<dim3(NB*NBOX), 256, 0, stream>>>(xin, W, bias, gdata, gint, win, acc);
    k_final<<<1, 1, 0, stream>>>(acc, out);
}